// Round 6
// baseline (131.759 us; speedup 1.0000x reference)
//
#include <hip/hip_runtime.h>
#include <hip/hip_bf16.h>
#include <math.h>

// ---- problem constants ----
#define B_ROWS 512
#define D_K    512
#define C_CLS  100000

#define COS_M 0.8775825618903728f
#define SIN_M 0.479425538604203f
#define TH_C  (-0.8775825618903728f)    // cos(pi - m)
#define MM_C  0.2397127693021015f       // sin(pi - m) * m

#define LOG2E_S 92.33248261689366f      // 64 * log2(e)
#define M0      92.4f                   // fixed softmax bound: |cos|<=1 -> |L|<=92.33
#define LN2F    0.6931471805599453f

// ---- GEMM tile config ----
#define BM 128                          // rows per block; 4 rowblocks cover 512
#define BN 64                           // classes per chunk
#define NCHUNK 1563                     // ceil(100000/64); tail rows rn=0
#define CPS 13                          // chunks per strip
#define NSTRIP 121                      // ceil(1563/13); last strip has 3 chunks

typedef __attribute__((ext_vector_type(8))) short short8;
typedef __attribute__((ext_vector_type(4))) float f32x4;

__device__ inline unsigned short f2bf(float f) {
    unsigned int u = __float_as_uint(f);
    u += 0x7fffu + ((u >> 16) & 1u);
    return (unsigned short)(u >> 16);
}
__device__ inline float fexp2(float x) {
#if __has_builtin(__builtin_amdgcn_exp2f)
    return __builtin_amdgcn_exp2f(x);
#else
    return exp2f(x);
#endif
}
__device__ inline void gload16(const void* g, void* lds) {
    __builtin_amdgcn_global_load_lds(
        (const __attribute__((address_space(1))) unsigned int*)g,
        (__attribute__((address_space(3))) unsigned int*)lds, 16, 0, 0);
}
#define VMCNT0() asm volatile("s_waitcnt vmcnt(0)" ::: "memory")

// ---------------- kernel 0: normalize x rows -> bf16 (+ 1/|x|) ----------------
__global__ __launch_bounds__(256) void xnorm_kernel(const float* __restrict__ x,
                                                    unsigned short* __restrict__ xnb,
                                                    float* __restrict__ xrn) {
    const int row = blockIdx.x;
    const int t = threadIdx.x;
    float a = x[row * D_K + t];
    float b = x[row * D_K + t + 256];
    float s = a * a + b * b;
    s += __shfl_xor(s, 1);  s += __shfl_xor(s, 2);  s += __shfl_xor(s, 4);
    s += __shfl_xor(s, 8);  s += __shfl_xor(s, 16); s += __shfl_xor(s, 32);
    __shared__ float sS[4];
    __shared__ float rn_sh;
    if ((t & 63) == 0) sS[t >> 6] = s;
    __syncthreads();
    if (t == 0) {
        float rn = 1.0f / sqrtf(sS[0] + sS[1] + sS[2] + sS[3]);
        rn_sh = rn;
        xrn[row] = rn;
    }
    __syncthreads();
    const float rn = rn_sh;
    xnb[row * D_K + t]       = f2bf(a * rn);
    xnb[row * D_K + t + 256] = f2bf(b * rn);
}

// ---------------- kernel 1: fused strip GEMM (raw fp32 W, folded norms) ----------------
// 4 waves, BM=128 rows in registers (afr: 128 VGPR), strip of CPS chunks of 64 classes.
// Per kstep: stage next 64x64 k-slice (fp32->bf16 reg-staged, dbuf'd, ss+=v^2 folded),
// 16 MFMA/wave from LDS, 1 barrier. rnorm reduced at k==6, applied in exp at k==7.
// Grid 512 = 2 blocks/CU, all co-resident; XCD-quad swizzle groups a strip's 4
// rowblocks on one XCD so W's 4x re-read is L2-served.
__global__ __launch_bounds__(256, 2) void gemm_fused_kernel(
        const unsigned short* __restrict__ xnb,   // [512][512] bf16 normalized
        const float* __restrict__ w,              // [100000][512] fp32 raw
        float* __restrict__ partials) {           // [NSTRIP][512]
    const int t    = threadIdx.x;
    const int lane = t & 63;
    const int wid  = t >> 6;

    const int j    = blockIdx.x;
    const int xcd  = j & 7;
    const int slot = j >> 3;
    const int s    = xcd + 8 * (slot >> 2);   // strip
    const int rb   = slot & 3;                // rowblock
    if (s >= NSTRIP) return;
    const int R0    = rb * BM;
    const int cbase = s * (CPS * BN);
    const int rem   = NCHUNK - s * CPS;
    const int nch   = rem < CPS ? rem : CPS;

    __shared__ char  smem[2 * 8192];          // B dbuf (also A-prologue bounce)
    __shared__ float rnsh[64];

    const int l8    = lane >> 3;
    const int cbs   = ((lane & 7) ^ l8) << 4; // pre-swizzled global source byte-col
    const int cl    = lane & 15;
    const int khalf = (lane >> 4) << 4;
    const int xorv  = (lane & 7) << 4;

    // ---- A prologue: 128 rows x 512 k -> registers via LDS bounce ----
    short8 afr[2][16];
    const char* gA = (const char*)xnb;
#pragma unroll
    for (int ks = 0; ks < 8; ++ks) {
#pragma unroll
        for (int i = 0; i < 4; ++i) {
            const int row = i * 32 + wid * 8 + l8;
            gload16(gA + (size_t)(R0 + row) * 1024 + ks * 128 + cbs,
                    smem + (i * 4 + wid) * 1024);
        }
        VMCNT0();
        __syncthreads();
#pragma unroll
        for (int m = 0; m < 2; ++m)
#pragma unroll
            for (int kk = 0; kk < 2; ++kk) {
                const int r = wid * 32 + m * 16 + cl;
                afr[m][ks * 2 + kk] =
                    *(const short8*)(smem + r * 128 + ((kk * 64 + khalf) ^ xorv));
            }
        __syncthreads();
    }

    // ---- staging identity ----
    const int rA   = t >> 3;                  // class row 0..31 (and rA+32)
    const int il   = t & 7;
    const int srcg = il ^ (rA & 7);           // logical granule for phys granule il

    float ssA = 0.f, ssB = 0.f;
    float sums[8] = {0.f, 0.f, 0.f, 0.f, 0.f, 0.f, 0.f, 0.f};

    // ---- prologue stage: chunk 0, slice 0 -> buf 0 ----
    {
        int c0 = cbase + rA;       c0 = c0 < C_CLS ? c0 : C_CLS - 1;
        int c1 = cbase + rA + 32;  c1 = c1 < C_CLS ? c1 : C_CLS - 1;
        const float* s0 = w + (size_t)c0 * D_K + srcg * 8;
        const float* s1 = w + (size_t)c1 * D_K + srcg * 8;
        float4 qa0 = *(const float4*)s0, qb0 = *(const float4*)(s0 + 4);
        float4 qa1 = *(const float4*)s1, qb1 = *(const float4*)(s1 + 4);
        ssA += qa0.x*qa0.x + qa0.y*qa0.y + qa0.z*qa0.z + qa0.w*qa0.w
             + qb0.x*qb0.x + qb0.y*qb0.y + qb0.z*qb0.z + qb0.w*qb0.w;
        ssB += qa1.x*qa1.x + qa1.y*qa1.y + qa1.z*qa1.z + qa1.w*qa1.w
             + qb1.x*qb1.x + qb1.y*qb1.y + qb1.z*qb1.z + qb1.w*qb1.w;
        short8 h0, h1;
        h0[0]=(short)f2bf(qa0.x); h0[1]=(short)f2bf(qa0.y); h0[2]=(short)f2bf(qa0.z); h0[3]=(short)f2bf(qa0.w);
        h0[4]=(short)f2bf(qb0.x); h0[5]=(short)f2bf(qb0.y); h0[6]=(short)f2bf(qb0.z); h0[7]=(short)f2bf(qb0.w);
        h1[0]=(short)f2bf(qa1.x); h1[1]=(short)f2bf(qa1.y); h1[2]=(short)f2bf(qa1.z); h1[3]=(short)f2bf(qa1.w);
        h1[4]=(short)f2bf(qb1.x); h1[5]=(short)f2bf(qb1.y); h1[6]=(short)f2bf(qb1.z); h1[7]=(short)f2bf(qb1.w);
        *(short8*)(smem + t * 16) = h0;
        *(short8*)(smem + 4096 + t * 16) = h1;
    }
    __syncthreads();

    for (int ci = 0; ci < nch; ++ci) {
        f32x4 acc[2][4];
#pragma unroll
        for (int m = 0; m < 2; ++m)
#pragma unroll
            for (int n = 0; n < 4; ++n) acc[m][n] = (f32x4){0.f, 0.f, 0.f, 0.f};

#pragma unroll
        for (int k = 0; k < 8; ++k) {
            const bool do_stage = (ci * 8 + k + 1) < nch * 8;
            const int  ci2 = (k == 7) ? ci + 1 : ci;
            const int  k2  = (k + 1) & 7;
            // issue next-slice fp32 loads early (hidden under MFMA)
            float4 qa0, qb0, qa1, qb1;
            if (do_stage) {
                int c0 = cbase + ci2 * 64 + rA;       c0 = c0 < C_CLS ? c0 : C_CLS - 1;
                int c1 = cbase + ci2 * 64 + rA + 32;  c1 = c1 < C_CLS ? c1 : C_CLS - 1;
                const float* s0 = w + (size_t)c0 * D_K + k2 * 64 + srcg * 8;
                const float* s1 = w + (size_t)c1 * D_K + k2 * 64 + srcg * 8;
                qa0 = *(const float4*)s0; qb0 = *(const float4*)(s0 + 4);
                qa1 = *(const float4*)s1; qb1 = *(const float4*)(s1 + 4);
            }
            // MFMA from buf[k&1]
            const char* sB = smem + (k & 1) * 8192;
#pragma unroll
            for (int kk = 0; kk < 2; ++kk) {
                const int coff = (kk * 64 + khalf) ^ xorv;
                short8 bfr[4];
#pragma unroll
                for (int n = 0; n < 4; ++n)
                    bfr[n] = *(const short8*)(sB + (n * 16 + cl) * 128 + coff);
#pragma unroll
                for (int m = 0; m < 2; ++m)
#pragma unroll
                    for (int n = 0; n < 4; ++n)
                        acc[m][n] = __builtin_amdgcn_mfma_f32_16x16x32_bf16(
                            afr[m][k * 2 + kk], bfr[n], acc[m][n], 0, 0, 0);
            }
            // convert + write buf[(k+1)&1], fold ss += v^2
            if (do_stage) {
                ssA += qa0.x*qa0.x + qa0.y*qa0.y + qa0.z*qa0.z + qa0.w*qa0.w
                     + qb0.x*qb0.x + qb0.y*qb0.y + qb0.z*qb0.z + qb0.w*qb0.w;
                ssB += qa1.x*qa1.x + qa1.y*qa1.y + qa1.z*qa1.z + qa1.w*qa1.w
                     + qb1.x*qb1.x + qb1.y*qb1.y + qb1.z*qb1.z + qb1.w*qb1.w;
                short8 h0, h1;
                h0[0]=(short)f2bf(qa0.x); h0[1]=(short)f2bf(qa0.y); h0[2]=(short)f2bf(qa0.z); h0[3]=(short)f2bf(qa0.w);
                h0[4]=(short)f2bf(qb0.x); h0[5]=(short)f2bf(qb0.y); h0[6]=(short)f2bf(qb0.z); h0[7]=(short)f2bf(qb0.w);
                h1[0]=(short)f2bf(qa1.x); h1[1]=(short)f2bf(qa1.y); h1[2]=(short)f2bf(qa1.z); h1[3]=(short)f2bf(qa1.w);
                h1[4]=(short)f2bf(qb1.x); h1[5]=(short)f2bf(qb1.y); h1[6]=(short)f2bf(qb1.z); h1[7]=(short)f2bf(qb1.w);
                char* dB = smem + ((k + 1) & 1) * 8192;
                *(short8*)(dB + t * 16) = h0;
                *(short8*)(dB + 4096 + t * 16) = h1;
            }
            if (k == 6) {
                // ss now covers all 8 slices of THIS chunk -> reduce to rnorm
                float a = ssA, b = ssB;
                a += __shfl_xor(a, 1); a += __shfl_xor(a, 2); a += __shfl_xor(a, 4);
                b += __shfl_xor(b, 1); b += __shfl_xor(b, 2); b += __shfl_xor(b, 4);
                if (il == 0) {
                    const int cA = cbase + ci * 64 + rA;
                    rnsh[rA]      = (cA      < C_CLS) ? (1.0f / sqrtf(a)) : 0.0f;
                    rnsh[rA + 32] = (cA + 32 < C_CLS) ? (1.0f / sqrtf(b)) : 0.0f;
                }
                ssA = 0.f; ssB = 0.f;
            }
            if (k == 7) {
                // fixed-M0 accumulation with post-dot normalization
                float rl[4];
#pragma unroll
                for (int n = 0; n < 4; ++n) rl[n] = rnsh[n * 16 + cl] * LOG2E_S;
#pragma unroll
                for (int m = 0; m < 2; ++m)
#pragma unroll
                    for (int jj = 0; jj < 4; ++jj)
#pragma unroll
                        for (int n = 0; n < 4; ++n)
                            sums[m * 4 + jj] +=
                                fexp2(fmaf(acc[m][n][jj], rl[n], -M0));
            }
            __syncthreads();
        }
    }

    // ---- strip epilogue: reduce tracked rows across their 16 col-lanes ----
#pragma unroll
    for (int m = 0; m < 2; ++m)
#pragma unroll
        for (int jj = 0; jj < 4; ++jj) {
            float v = sums[m * 4 + jj];
            v += __shfl_xor(v, 1);
            v += __shfl_xor(v, 2);
            v += __shfl_xor(v, 4);
            v += __shfl_xor(v, 8);
            if ((lane & 15) == 0) {
                const int r = R0 + wid * 32 + m * 16 + (lane >> 4) * 4 + jj;
                partials[s * B_ROWS + r] = v;
            }
        }
}

// ---------------- kernel 2: target-class cosine (fp32 exact) ----------------
__global__ __launch_bounds__(256) void tdot_kernel(const float* __restrict__ x,
                                                   const float* __restrict__ w,
                                                   const int* __restrict__ tgt,
                                                   const float* __restrict__ xrn,
                                                   float* __restrict__ tdot) {
    const int wid = threadIdx.x >> 6;
    const int lane = threadIdx.x & 63;
    const int b = blockIdx.x * 4 + wid;
    const int tg = tgt[b];
    const float* xr = x + (size_t)b * D_K + lane * 8;
    const float* wr = w + (size_t)tg * D_K + lane * 8;
    float4 xa = *(const float4*)xr;
    float4 xb = *(const float4*)(xr + 4);
    float4 wa = *(const float4*)wr;
    float4 wb = *(const float4*)(wr + 4);
    float xw = xa.x * wa.x + xa.y * wa.y + xa.z * wa.z + xa.w * wa.w
             + xb.x * wb.x + xb.y * wb.y + xb.z * wb.z + xb.w * wb.w;
    float ww = wa.x * wa.x + wa.y * wa.y + wa.z * wa.z + wa.w * wa.w
             + wb.x * wb.x + wb.y * wb.y + wb.z * wb.z + wb.w * wb.w;
#pragma unroll
    for (int m = 1; m < 64; m <<= 1) {
        xw += __shfl_xor(xw, m);
        ww += __shfl_xor(ww, m);
    }
    if (lane == 0) tdot[b] = xw * xrn[b] / sqrtf(ww);
}

// ---------------- kernel 3: per-row loss (margin fixup) + mean ----------------
__global__ __launch_bounds__(512) void final_kernel(const float* __restrict__ partials,
                                                    const float* __restrict__ tdot,
                                                    float* __restrict__ out) {
    const int b = threadIdx.x;   // 512 threads = 8 waves
    float s2 = 0.f;
    for (int s = 0; s < NSTRIP; ++s) s2 += partials[s * B_ROWS + b];
    const float cst = tdot[b];
    float c2 = 1.0f - cst * cst;
    c2 = fminf(fmaxf(c2, 0.0f), 1.0f);
    const float sine = sqrtf(c2);
    float phi = cst * COS_M - sine * SIN_M;
    phi = (cst > TH_C) ? phi : (cst - MM_C);
    const float Lt = cst * LOG2E_S;
    const float Lp = phi * LOG2E_S;
    // swap plain-target term for margin term in the denominator
    s2 = s2 - fexp2(Lt - M0) + fexp2(Lp - M0);
    float loss = LN2F * (M0 + log2f(s2) - Lp);
    loss += __shfl_xor(loss, 1);  loss += __shfl_xor(loss, 2);
    loss += __shfl_xor(loss, 4);  loss += __shfl_xor(loss, 8);
    loss += __shfl_xor(loss, 16); loss += __shfl_xor(loss, 32);
    __shared__ float sW[8];
    if ((b & 63) == 0) sW[b >> 6] = loss;
    __syncthreads();
    if (b == 0) {
        float tot = 0.f;
#pragma unroll
        for (int wv = 0; wv < 8; ++wv) tot += sW[wv];
        out[0] = tot * (1.0f / (float)B_ROWS);
    }
}

extern "C" void kernel_launch(void* const* d_in, const int* in_sizes, int n_in,
                              void* d_out, int out_size, void* d_ws, size_t ws_size,
                              hipStream_t stream) {
    const float* x = (const float*)d_in[0];
    const float* w = (const float*)d_in[1];
    const int* tgt = (const int*)d_in[2];
    float* out = (float*)d_out;

    char* ws = (char*)d_ws;
    size_t off = 0;
    unsigned short* xnb = (unsigned short*)(ws + off);
    off += (size_t)B_ROWS * D_K * 2;                   // 512 KB
    off = (off + 255) & ~(size_t)255;
    float* xrn = (float*)(ws + off);
    off += B_ROWS * 4;
    off = (off + 255) & ~(size_t)255;
    float* partials = (float*)(ws + off);
    off += (size_t)NSTRIP * B_ROWS * 4;                // 248 KB
    off = (off + 255) & ~(size_t)255;
    float* tdot = (float*)(ws + off);
    off += B_ROWS * 4;

    xnorm_kernel<<<B_ROWS, 256, 0, stream>>>(x, xnb, xrn);
    tdot_kernel<<<B_ROWS / 4, 256, 0, stream>>>(x, w, tgt, xrn, tdot);
    gemm_fused_kernel<<<512, 256, 0, stream>>>(xnb, w, partials);
    final_kernel<<<1, 512, 0, stream>>>(partials, tdot, out);
}

// Round 7
// 109.014 us; speedup vs baseline: 1.2086x; 1.2086x over previous
//
#include <hip/hip_runtime.h>
#include <hip/hip_bf16.h>
#include <math.h>

// ---- problem constants ----
#define B_ROWS 512
#define D_K    512
#define C_CLS  100000
#define C_PAD  100032                   // NCHUNK*64 (pad rows written as fp8 zeros)

#define COS_M 0.8775825618903728f
#define SIN_M 0.479425538604203f
#define TH_C  (-0.8775825618903728f)    // cos(pi - m)
#define MM_C  0.2397127693021015f       // sin(pi - m) * m

#define LOG2E_S 92.33248261689366f      // 64 * log2(e)
#define M0      92.4f                   // fixed softmax bound: |cos|<=1 -> |L|<=92.33
#define LN2F    0.6931471805599453f

// ---- GEMM tile config ----
#define BM 256                          // rows per block; 2 rowblocks cover 512
#define BN 64                           // classes per chunk
#define NCHUNK 1563                     // ceil(100000/64)
#define CPS 7                           // chunks per strip
#define NSTRIP 224                      // ceil(1563/7); last strip has 2 chunks

typedef __attribute__((ext_vector_type(4))) float f32x4;
typedef long long i64;

__device__ inline float fexp2(float x) {
#if __has_builtin(__builtin_amdgcn_exp2f)
    return __builtin_amdgcn_exp2f(x);
#else
    return exp2f(x);
#endif
}
__device__ inline void gload16(const void* g, void* lds) {
    __builtin_amdgcn_global_load_lds(
        (const __attribute__((address_space(1))) unsigned int*)g,
        (__attribute__((address_space(3))) unsigned int*)lds, 16, 0, 0);
}
#define VMCNT0() asm volatile("s_waitcnt vmcnt(0)" ::: "memory")
#define VMCNT6() asm volatile("s_waitcnt vmcnt(6)" ::: "memory")
#define RAWBAR() __builtin_amdgcn_s_barrier()

// ---------------- kernel 0: row-normalize -> fp8 e4m3 (4 rows/block) ----------------
// in[r][0..511] fp32 -> out fp8 (OCP e4m3) normalized; rows >= nvalid get zeros.
// Optionally records 1/|row| to rnout.
__global__ __launch_bounds__(256) void rownorm8_kernel(const float* __restrict__ in,
                                                       uint2* __restrict__ out,
                                                       float* __restrict__ rnout,
                                                       int nvalid) {
    const int wid = threadIdx.x >> 6;
    const int lane = threadIdx.x & 63;
    const int r = blockIdx.x * 4 + wid;
    if (r >= nvalid) {
        out[(size_t)r * 64 + lane] = make_uint2(0u, 0u);
        return;
    }
    const float* row = in + (size_t)r * D_K + lane * 8;
    float4 a = *(const float4*)row;
    float4 b = *(const float4*)(row + 4);
    float ss = a.x * a.x + a.y * a.y + a.z * a.z + a.w * a.w
             + b.x * b.x + b.y * b.y + b.z * b.z + b.w * b.w;
    ss += __shfl_xor(ss, 1);  ss += __shfl_xor(ss, 2);  ss += __shfl_xor(ss, 4);
    ss += __shfl_xor(ss, 8);  ss += __shfl_xor(ss, 16); ss += __shfl_xor(ss, 32);
    const float rn = 1.0f / sqrtf(ss);
    int u0 = __builtin_amdgcn_cvt_pk_fp8_f32(a.x * rn, a.y * rn, 0, false);
    u0     = __builtin_amdgcn_cvt_pk_fp8_f32(a.z * rn, a.w * rn, u0, true);
    int u1 = __builtin_amdgcn_cvt_pk_fp8_f32(b.x * rn, b.y * rn, 0, false);
    u1     = __builtin_amdgcn_cvt_pk_fp8_f32(b.z * rn, b.w * rn, u1, true);
    out[(size_t)r * 64 + lane] = make_uint2((unsigned)u0, (unsigned)u1);
    if (rnout != nullptr && lane == 0) rnout[r] = rn;
}

// ---------------- kernel 1: fp8 strip GEMM + fixed-M0 sumexp ----------------
// 4 waves; each wave owns 64 rows (A fp8 in regs: a8[4][16] = 128 VGPR).
// B: 64x64 fp8 slice = 4KB, ONE global_load_lds per kstep, 8-buffer ring,
// constant vmcnt(6) via dummy tail stages. Granule-XOR swizzle (g ^ (row>>1)&3)
// keeps ds_read_b64 near conflict-free and is gload_lds-compatible.
__global__ __launch_bounds__(256, 2) void gemm_fp8_kernel(
        const unsigned char* __restrict__ xnb8,   // [512][512] fp8 normalized
        const unsigned char* __restrict__ wn8,    // [C_PAD][512] fp8 normalized (pad=0)
        float* __restrict__ partials) {           // [NSTRIP][512]
    const int t    = threadIdx.x;
    const int lane = t & 63;
    const int wid  = t >> 6;
    const int cl   = lane & 15;
    const int hi   = lane >> 4;

    // XCD-pair swizzle: both rowblocks of a strip on one XCD. Bijective for 448.
    const int j    = blockIdx.x;
    const int xcd  = j & 7;
    const int slot = j >> 3;
    const int s    = xcd + 8 * (slot >> 1);
    const int rb   = slot & 1;
    if (s >= NSTRIP) return;
    const int R0    = rb * BM;
    const int cbase = s * (CPS * BN);
    const int rem   = NCHUNK - s * CPS;
    const int nch   = rem < CPS ? rem : CPS;
    const int nst   = nch * 8;

    __shared__ char smem[8 * 4096];   // 32 KB B ring

    // staging identity: one 4KB slice per kstep; thread t stages row t>>2, granule t&3
    const int srow = t >> 2;
    const int sgl  = (t & 3) ^ ((srow >> 1) & 3);   // pre-swizzled source granule

#define STAGE(st_src, buf)                                                      \
    {                                                                           \
        const int _ci = (st_src) >> 3, _k = (st_src) & 7;                       \
        gload16(wn8 + ((size_t)(cbase + _ci * 64 + srow)) * 512 + _k * 64 +     \
                    sgl * 16,                                                   \
                smem + (buf) * 4096 + t * 16);                                  \
    }

    // ---- B prologue: stages 0..6 ----
#pragma unroll
    for (int p = 0; p < 7; ++p) STAGE(p, p);

    // ---- A: 64 rows/wave, full K=512, fp8 in registers (direct global loads) ----
    i64 a8[4][16];
#pragma unroll
    for (int m = 0; m < 4; ++m) {
        const unsigned char* ap = xnb8 + (size_t)(R0 + wid * 64 + m * 16 + cl) * 512 + hi * 8;
#pragma unroll
        for (int ks = 0; ks < 8; ++ks) {
#pragma unroll
            for (int kk = 0; kk < 2; ++kk)
                a8[m][ks * 2 + kk] = *(const i64*)(ap + ks * 64 + kk * 32);
        }
    }

    float sums[16];
#pragma unroll
    for (int i = 0; i < 16; ++i) sums[i] = 0.f;

    const int rdbase = ((hi & 1) * 8);   // byte-in-granule for this lane's k-slot

    for (int ci = 0; ci < nch; ++ci) {
        f32x4 acc[4][4];
#pragma unroll
        for (int m = 0; m < 4; ++m)
#pragma unroll
            for (int n = 0; n < 4; ++n) acc[m][n] = (f32x4){0.f, 0.f, 0.f, 0.f};

#pragma unroll
        for (int k = 0; k < 8; ++k) {
            const int st  = ci * 8 + k;
            VMCNT6();
            RAWBAR();
            // issue stage st+7 (dummy re-stage of the last slice at the tail)
            {
                const int st7 = st + 7;
                const int src = st7 > nst - 1 ? nst - 1 : st7;
                STAGE(src, st7 & 7);
            }
            const char* sB = smem + (st & 7) * 4096;
#pragma unroll
            for (int kk = 0; kk < 2; ++kk) {
                i64 bfr[4];
#pragma unroll
                for (int n = 0; n < 4; ++n) {
                    const int row = n * 16 + cl;
                    const int pg  = (kk * 2 + (hi >> 1)) ^ ((cl >> 1) & 3);
                    bfr[n] = *(const i64*)(sB + row * 64 + pg * 16 + rdbase);
                }
#pragma unroll
                for (int m = 0; m < 4; ++m)
#pragma unroll
                    for (int n = 0; n < 4; ++n)
                        acc[m][n] = __builtin_amdgcn_mfma_f32_16x16x32_fp8_fp8(
                            a8[m][k * 2 + kk], bfr[n], acc[m][n], 0, 0, 0);
            }
        }

        // fixed-M0 accumulation: sums += 2^(S*log2e*cos - M0) (pad rows: acc=0 -> ~2^-92)
#pragma unroll
        for (int m = 0; m < 4; ++m)
#pragma unroll
            for (int jj = 0; jj < 4; ++jj)
#pragma unroll
                for (int n = 0; n < 4; ++n)
                    sums[m * 4 + jj] += fexp2(fmaf(acc[m][n][jj], LOG2E_S, -M0));
    }
#undef STAGE

    // ---- strip epilogue: reduce tracked rows across their 16 col-lanes ----
#pragma unroll
    for (int m = 0; m < 4; ++m)
#pragma unroll
        for (int jj = 0; jj < 4; ++jj) {
            float v = sums[m * 4 + jj];
            v += __shfl_xor(v, 1);
            v += __shfl_xor(v, 2);
            v += __shfl_xor(v, 4);
            v += __shfl_xor(v, 8);
            if (cl == 0) {
                const int r = R0 + wid * 64 + m * 16 + hi * 4 + jj;
                partials[s * B_ROWS + r] = v;
            }
        }
}

// ---------------- kernel 2: target-class cosine (fp32 exact) ----------------
__global__ __launch_bounds__(256) void tdot_kernel(const float* __restrict__ x,
                                                   const float* __restrict__ w,
                                                   const int* __restrict__ tgt,
                                                   const float* __restrict__ xrn,
                                                   float* __restrict__ tdot) {
    const int wid = threadIdx.x >> 6;
    const int lane = threadIdx.x & 63;
    const int b = blockIdx.x * 4 + wid;
    const int tg = tgt[b];
    const float* xr = x + (size_t)b * D_K + lane * 8;
    const float* wr = w + (size_t)tg * D_K + lane * 8;
    float4 xa = *(const float4*)xr;
    float4 xb = *(const float4*)(xr + 4);
    float4 wa = *(const float4*)wr;
    float4 wb = *(const float4*)(wr + 4);
    float xw = xa.x * wa.x + xa.y * wa.y + xa.z * wa.z + xa.w * wa.w
             + xb.x * wb.x + xb.y * wb.y + xb.z * wb.z + xb.w * wb.w;
    float ww = wa.x * wa.x + wa.y * wa.y + wa.z * wa.z + wa.w * wa.w
             + wb.x * wb.x + wb.y * wb.y + wb.z * wb.z + wb.w * wb.w;
#pragma unroll
    for (int m = 1; m < 64; m <<= 1) {
        xw += __shfl_xor(xw, m);
        ww += __shfl_xor(ww, m);
    }
    if (lane == 0) tdot[b] = xw * xrn[b] / sqrtf(ww);
}

// ---------------- kernel 3: per-row loss (margin fixup) + mean ----------------
__global__ __launch_bounds__(512) void final_kernel(const float* __restrict__ partials,
                                                    const float* __restrict__ tdot,
                                                    float* __restrict__ out) {
    const int b = threadIdx.x;   // 512 threads = 8 waves
    float s2 = 0.f;
    for (int s = 0; s < NSTRIP; ++s) s2 += partials[s * B_ROWS + b];
    const float cst = tdot[b];
    float c2 = 1.0f - cst * cst;
    c2 = fminf(fmaxf(c2, 0.0f), 1.0f);
    const float sine = sqrtf(c2);
    float phi = cst * COS_M - sine * SIN_M;
    phi = (cst > TH_C) ? phi : (cst - MM_C);
    const float Lt = cst * LOG2E_S;
    const float Lp = phi * LOG2E_S;
    // swap plain-target term for margin term in the denominator
    s2 = s2 - fexp2(Lt - M0) + fexp2(Lp - M0);
    float loss = LN2F * (M0 + log2f(s2) - Lp);
    loss += __shfl_xor(loss, 1);  loss += __shfl_xor(loss, 2);
    loss += __shfl_xor(loss, 4);  loss += __shfl_xor(loss, 8);
    loss += __shfl_xor(loss, 16); loss += __shfl_xor(loss, 32);
    __shared__ float sW[8];
    if ((b & 63) == 0) sW[b >> 6] = loss;
    __syncthreads();
    if (b == 0) {
        float tot = 0.f;
#pragma unroll
        for (int wv = 0; wv < 8; ++wv) tot += sW[wv];
        out[0] = tot * (1.0f / (float)B_ROWS);
    }
}

extern "C" void kernel_launch(void* const* d_in, const int* in_sizes, int n_in,
                              void* d_out, int out_size, void* d_ws, size_t ws_size,
                              hipStream_t stream) {
    const float* x = (const float*)d_in[0];
    const float* w = (const float*)d_in[1];
    const int* tgt = (const int*)d_in[2];
    float* out = (float*)d_out;

    char* ws = (char*)d_ws;
    size_t off = 0;
    unsigned char* xnb8 = (unsigned char*)(ws + off);
    off += (size_t)B_ROWS * D_K;                       // 256 KB
    off = (off + 255) & ~(size_t)255;
    unsigned char* wn8 = (unsigned char*)(ws + off);
    off += (size_t)C_PAD * D_K;                        // 51.2 MB
    off = (off + 255) & ~(size_t)255;
    float* xrn = (float*)(ws + off);
    off += B_ROWS * 4;
    off = (off + 255) & ~(size_t)255;
    float* partials = (float*)(ws + off);
    off += (size_t)NSTRIP * B_ROWS * 4;                // 459 KB
    off = (off + 255) & ~(size_t)255;
    float* tdot = (float*)(ws + off);
    off += B_ROWS * 4;

    rownorm8_kernel<<<B_ROWS / 4, 256, 0, stream>>>(x, (uint2*)xnb8, xrn, B_ROWS);
    rownorm8_kernel<<<C_PAD / 4, 256, 0, stream>>>(w, (uint2*)wn8, nullptr, C_CLS);
    tdot_kernel<<<B_ROWS / 4, 256, 0, stream>>>(x, w, tgt, xrn, tdot);
    gemm_fp8_kernel<<<NSTRIP * 2, 256, 0, stream>>>(xnb8, wn8, partials);
    final_kernel<<<1, 512, 0, stream>>>(partials, tdot, out);
}